// Round 1
// baseline (1200.572 us; speedup 1.0000x reference)
//
#include <hip/hip_runtime.h>
#include <math.h>

#define H 1024
#define Bb 64
#define L 2048
#define V 32000
#define P 128
#define NC 16
#define LC (L/NC)   // 128 l's per chunk

// ---------------- embedding gather ----------------
__global__ void k_embed(const int* __restrict__ seq, const float* __restrict__ emb,
                        float* __restrict__ x) {
  int b = blockIdx.x;
  int t = threadIdx.x;                 // 256 threads, H/4 = 256 float4
  long row = (long)seq[b];
  const float4* src = (const float4*)(emb + row * H);
  float4* dst = (float4*)(x + (size_t)b * H);
  dst[t] = src[t];
}

// ---------------- generic tiled skinny GEMM: C[64 x JT] = A[64 x K] * W[JT x K]^T ----------------
// TJ = columns per thread (2 or 4) -> JT = 16*TJ. ACT: 0=none, 1=tanh.
template<int TJ, int ACT>
__device__ __forceinline__ void gemm_tile(
    const float* __restrict__ A, int lda,
    const float* __restrict__ W, int ldw,   // W pre-offset to row j0
    const float* __restrict__ bias,         // pre-offset to j0
    float* __restrict__ C, int ldc,         // pre-offset to column j0
    int K)
{
  constexpr int JT = TJ * 16;
  __shared__ float As[64][36];   // pad 36: 2-way bank aliasing only (free), float4-aligned rows
  __shared__ float Ws[JT][36];
  const int t  = threadIdx.x;
  const int tb = t & 15;         // b-group: b = tb*4 + bb
  const int tj = t >> 4;         // j-group: j = tj*TJ + jj

  float acc[4][TJ];
#pragma unroll
  for (int i = 0; i < 4; ++i)
#pragma unroll
    for (int j = 0; j < TJ; ++j) acc[i][j] = 0.f;

  for (int k0 = 0; k0 < K; k0 += 32) {
    // stage A tile 64x32 (512 float4, 2 per thread)
#pragma unroll
    for (int r = 0; r < 2; ++r) {
      int i4 = r * 256 + t;
      int bi = i4 >> 3;
      int k4 = (i4 & 7) << 2;
      float4 v = *(const float4*)(A + (size_t)bi * lda + k0 + k4);
      As[bi][k4] = v.x; As[bi][k4+1] = v.y; As[bi][k4+2] = v.z; As[bi][k4+3] = v.w;
    }
    // stage W tile JTx32
#pragma unroll
    for (int r = 0; r < JT/32; ++r) {
      int i4 = r * 256 + t;
      int ji = i4 >> 3;
      int k4 = (i4 & 7) << 2;
      float4 v = *(const float4*)(W + (size_t)ji * ldw + k0 + k4);
      Ws[ji][k4] = v.x; Ws[ji][k4+1] = v.y; Ws[ji][k4+2] = v.z; Ws[ji][k4+3] = v.w;
    }
    __syncthreads();
#pragma unroll
    for (int ks = 0; ks < 32; ks += 4) {
      float4 av[4], wv[TJ];
#pragma unroll
      for (int bb = 0; bb < 4; ++bb) av[bb] = *(const float4*)&As[tb*4+bb][ks];
#pragma unroll
      for (int jj = 0; jj < TJ; ++jj) wv[jj] = *(const float4*)&Ws[tj*TJ+jj][ks];
#pragma unroll
      for (int bb = 0; bb < 4; ++bb)
#pragma unroll
        for (int jj = 0; jj < TJ; ++jj) {
          acc[bb][jj] += av[bb].x*wv[jj].x + av[bb].y*wv[jj].y
                       + av[bb].z*wv[jj].z + av[bb].w*wv[jj].w;
        }
    }
    __syncthreads();
  }
#pragma unroll
  for (int bb = 0; bb < 4; ++bb) {
    int b = tb*4 + bb;
#pragma unroll
    for (int jj = 0; jj < TJ; ++jj) {
      float v = acc[bb][jj] + bias[tj*TJ + jj];
      if (ACT == 1) v = tanhf(v);
      C[(size_t)b * ldc + tj*TJ + jj] = v;
    }
  }
}

// gi/gh gates: 96 blocks x 64 rows of the combined [x@W_ih^T | h@W_hh^T] (6H cols)
__global__ __launch_bounds__(256) void k_gates(
    const float* __restrict__ x, const float* __restrict__ h,
    const float* __restrict__ W_ih, const float* __restrict__ W_hh,
    const float* __restrict__ b_ih, const float* __restrict__ b_hh,
    float* __restrict__ gates)
{
  int j0 = blockIdx.x * 64;
  if (j0 < 3*H) {
    gemm_tile<4,0>(x, H, W_ih + (size_t)j0*H, H, b_ih + j0, gates + j0, 6*H, H);
  } else {
    int jh = j0 - 3*H;
    gemm_tile<4,0>(h, H, W_hh + (size_t)jh*H, H, b_hh + jh, gates + j0, 6*H, H);
  }
}

__global__ __launch_bounds__(256) void k_concat_gemm(
    const float* __restrict__ cat, const float* __restrict__ Wc,
    const float* __restrict__ bc, float* __restrict__ cat2)
{
  int j0 = blockIdx.x * 32;   // 32 blocks
  gemm_tile<2,1>(cat, 2*H, Wc + (size_t)j0*2*H, 2*H, bc + j0, cat2 + j0, H+P, 2*H);
}

__global__ __launch_bounds__(256) void k_out_gemm(
    const float* __restrict__ cat2, const float* __restrict__ Wo,
    const float* __restrict__ bo, float* __restrict__ out)
{
  int j0 = blockIdx.x * 64;   // 500 blocks
  gemm_tile<4,0>(cat2, H+P, Wo + (size_t)j0*(H+P), H+P, bo + j0, out + j0, V, H+P);
}

// ---------------- GRU gate combine ----------------
__global__ void k_gru_combine(const float* __restrict__ gates, const float* __restrict__ h,
                              float* __restrict__ cat, float* __restrict__ out_h) {
  int i = blockIdx.x * 256 + threadIdx.x;   // 65536
  int b = i >> 10, j = i & 1023;
  const float* g = gates + (size_t)b * 6 * H;
  float ir = g[j],       iz = g[j +   H], in_ = g[j + 2*H];
  float hr = g[j + 3*H], hz = g[j + 4*H], hn  = g[j + 5*H];
  float r = 1.f / (1.f + __expf(-(ir + hr)));
  float z = 1.f / (1.f + __expf(-(iz + hz)));
  float n = tanhf(in_ + r * hn);
  float hv = (1.f - z) * n + z * h[i];
  cat[(size_t)b * 2 * H + j] = hv;   // first half of concat input
  out_h[i] = hv;                     // h_new output
}

// ---------------- fused attention: energies + online-softmax context partials ----------------
__global__ __launch_bounds__(256) void k_energy(
    const float* __restrict__ cat, const float* __restrict__ enc,
    float* __restrict__ energies, float* __restrict__ part_m,
    float* __restrict__ part_d, float* __restrict__ part_vec)
{
  int b = blockIdx.y;
  int c = blockIdx.x;
  int t = threadIdx.x;
  int lane = t & 63, wid = t >> 6;
  __shared__ float red[4];
  float4 hv = *(const float4*)(cat + (size_t)b * 2 * H + t * 4);
  float m = -1e30f, d = 0.f;
  float4 acc = make_float4(0.f, 0.f, 0.f, 0.f);
  int l0 = c * LC;
  for (int li = 0; li < LC; ++li) {
    int l = l0 + li;
    float4 ev = *(const float4*)(enc + ((size_t)l * Bb + b) * H + t * 4);
    float p = hv.x*ev.x + hv.y*ev.y + hv.z*ev.z + hv.w*ev.w;
#pragma unroll
    for (int off = 32; off; off >>= 1) p += __shfl_down(p, off);
    if (lane == 0) red[wid] = p;
    __syncthreads();
    float e = red[0] + red[1] + red[2] + red[3];
    __syncthreads();
    if (t == 0) energies[(size_t)b * L + l] = e;
    float mn = fmaxf(m, e);
    float sc = __expf(m - mn);
    float w  = __expf(e - mn);
    d = d * sc + w;
    acc.x = acc.x * sc + w * ev.x;
    acc.y = acc.y * sc + w * ev.y;
    acc.z = acc.z * sc + w * ev.z;
    acc.w = acc.w * sc + w * ev.w;
    m = mn;
  }
  int pc = b * NC + c;
  if (t == 0) { part_m[pc] = m; part_d[pc] = d; }
  *(float4*)(part_vec + (size_t)pc * H + t * 4) = acc;
}

__global__ void k_attn_combine(const float* __restrict__ part_m, const float* __restrict__ part_d,
                               const float* __restrict__ part_vec,
                               float* __restrict__ cat, float* __restrict__ MD) {
  int b = blockIdx.x, t = threadIdx.x;
  float M = -1e30f;
  for (int c = 0; c < NC; ++c) M = fmaxf(M, part_m[b*NC + c]);
  float D = 0.f;
  for (int c = 0; c < NC; ++c) D += part_d[b*NC + c] * __expf(part_m[b*NC + c] - M);
  float4 ctx = make_float4(0.f, 0.f, 0.f, 0.f);
  for (int c = 0; c < NC; ++c) {
    float s = __expf(part_m[b*NC + c] - M);
    float4 v = *(const float4*)(part_vec + (size_t)(b*NC + c) * H + t * 4);
    ctx.x += s*v.x; ctx.y += s*v.y; ctx.z += s*v.z; ctx.w += s*v.w;
  }
  float inv = 1.f / D;
  ctx.x *= inv; ctx.y *= inv; ctx.z *= inv; ctx.w *= inv;
  *(float4*)(cat + (size_t)b * 2 * H + H + t * 4) = ctx;   // second half of concat input
  if (t == 0) { MD[b*2] = M; MD[b*2+1] = D; }
}

__global__ void k_weights(const float* __restrict__ energies, const float* __restrict__ MD,
                          float* __restrict__ outw) {
  int i = blockIdx.x * 256 + threadIdx.x;   // 131072
  int b = i >> 11;
  outw[i] = __expf(energies[i] - MD[b*2]) / MD[b*2+1];
}

__global__ void k_prior(const float* __restrict__ prior, float* __restrict__ cat2) {
  int i = blockIdx.x * 256 + threadIdx.x;   // 8192
  int b = i >> 7, p = i & 127;
  cat2[(size_t)b * (H+P) + H + p] = prior[i];
}

extern "C" void kernel_launch(void* const* d_in, const int* in_sizes, int n_in,
                              void* d_out, int out_size, void* d_ws, size_t ws_size,
                              hipStream_t stream) {
  const int*   seq   = (const int*)  d_in[0];
  const float* hprev = (const float*)d_in[1];   // [1,B,H] == [B,H]
  const float* enc   = (const float*)d_in[2];   // [L,B,H]
  const float* prior = (const float*)d_in[3];   // [B,P]
  const float* emb   = (const float*)d_in[4];   // [V,H]
  const float* W_ih  = (const float*)d_in[5];
  const float* W_hh  = (const float*)d_in[6];
  const float* b_ih  = (const float*)d_in[7];
  const float* b_hh  = (const float*)d_in[8];
  const float* Wc    = (const float*)d_in[9];   // [H,2H]
  const float* bc    = (const float*)d_in[10];
  const float* Wo    = (const float*)d_in[11];  // [V,H+P]
  const float* bo    = (const float*)d_in[12];

  float* out   = (float*)d_out;                 // [B,V]
  float* out_h = out + (size_t)Bb * V;          // [1,B,H]
  float* out_w = out_h + (size_t)Bb * H;        // [B,1,L]

  float* ws    = (float*)d_ws;
  float* x     = ws;                  // 65536
  float* gates = x     + 65536;       // 393216 : [B][6H] = [gi | gh]
  float* cat   = gates + 393216;      // 131072 : [B][2H] = [h_new | ctx]
  float* cat2  = cat   + 131072;      //  73728 : [B][H+P] = [concat_out | prior]
  float* energ = cat2  + 73728;       // 131072
  float* pm    = energ + 131072;      //   1024
  float* pd    = pm    + 1024;        //   1024
  float* MD    = pd    + 1024;        //    128
  float* pvec  = MD    + 128;         // 1048576 : [B][NC][H]

  k_embed<<<Bb, 256, 0, stream>>>(seq, emb, x);
  k_gates<<<96, 256, 0, stream>>>(x, hprev, W_ih, W_hh, b_ih, b_hh, gates);
  k_gru_combine<<<256, 256, 0, stream>>>(gates, hprev, cat, out_h);
  k_prior<<<32, 256, 0, stream>>>(prior, cat2);
  dim3 eg(NC, Bb);
  k_energy<<<eg, 256, 0, stream>>>(cat, enc, energ, pm, pd, pvec);
  k_attn_combine<<<Bb, 256, 0, stream>>>(pm, pd, pvec, cat, MD);
  k_weights<<<512, 256, 0, stream>>>(energ, MD, out_w);
  k_concat_gemm<<<32, 256, 0, stream>>>(cat, Wc, bc, cat2);
  k_out_gemm<<<500, 256, 0, stream>>>(cat2, Wo, bo, out);
}